// Round 3
// baseline (1505.939 us; speedup 1.0000x reference)
//
#include <hip/hip_runtime.h>
#include <hip/hip_bf16.h>

#define HF 64

// ---------------- proj news: relu([M,385] @ [385,64] + b) ----------------
__global__ __launch_bounds__(256) void k_proj_news(
    const float* __restrict__ A, const float* __restrict__ W,
    const float* __restrict__ b, float* __restrict__ out, int M)
{
    __shared__ float As[16][68];
    __shared__ float Ws[16][64];
    const int t = threadIdx.x;
    const int r0 = blockIdx.x * 64;
    const int rt = t >> 4, ct = t & 15;
    float acc[4][4] = {};

    for (int c0 = 0; c0 < 385; c0 += 16) {
        int lr = t >> 2, lk0 = (t & 3) * 4;
        #pragma unroll
        for (int j = 0; j < 4; ++j) {
            int k = c0 + lk0 + j;
            float v = 0.f;
            if ((r0 + lr) < M && k < 385) v = A[(size_t)(r0 + lr) * 385 + k];
            As[lk0 + j][lr] = v;
        }
        #pragma unroll
        for (int j = 0; j < 4; ++j) {
            int idx = j * 256 + t;
            int k = idx >> 6, col = idx & 63;
            float v = 0.f;
            if (c0 + k < 385) v = W[(size_t)(c0 + k) * 64 + col];
            Ws[k][col] = v;
        }
        __syncthreads();
        #pragma unroll
        for (int kk = 0; kk < 16; ++kk) {
            float4 a = *(const float4*)&As[kk][rt * 4];
            float4 w = *(const float4*)&Ws[kk][ct * 4];
            float av[4] = {a.x, a.y, a.z, a.w};
            float wv[4] = {w.x, w.y, w.z, w.w};
            #pragma unroll
            for (int i = 0; i < 4; ++i)
                #pragma unroll
                for (int j = 0; j < 4; ++j)
                    acc[i][j] += av[i] * wv[j];
        }
        __syncthreads();
    }
    float4 bv = *(const float4*)&b[ct * 4];
    float bb[4] = {bv.x, bv.y, bv.z, bv.w};
    #pragma unroll
    for (int i = 0; i < 4; ++i) {
        int row = r0 + rt * 4 + i;
        if (row < M) {
            float4 o;
            o.x = fmaxf(acc[i][0] + bb[0], 0.f);
            o.y = fmaxf(acc[i][1] + bb[1], 0.f);
            o.z = fmaxf(acc[i][2] + bb[2], 0.f);
            o.w = fmaxf(acc[i][3] + bb[3], 0.f);
            *(float4*)&out[(size_t)row * HF + ct * 4] = o;
        }
    }
}

// ---------------- proj company ----------------
__global__ __launch_bounds__(256) void k_proj_comp(
    const float* __restrict__ A, const float* __restrict__ W,
    const float* __restrict__ b, float* __restrict__ out, int M)
{
    int idx = blockIdx.x * blockDim.x + threadIdx.x;
    if (idx >= M * HF) return;
    int row = idx >> 6, col = idx & 63;
    float acc = b[col];
    #pragma unroll
    for (int k = 0; k < 24; ++k)
        acc += A[(size_t)row * 24 + k] * W[k * HF + col];
    out[idx] = fmaxf(acc, 0.f);
}

// ---------------- per-dst edge count ----------------
__global__ void k_count(const int* __restrict__ dst, int n, int base,
                        unsigned* __restrict__ cnt)
{
    for (int i = blockIdx.x * blockDim.x + threadIdx.x; i < n;
         i += gridDim.x * blockDim.x)
        atomicAdd(&cnt[base + dst[i]], 1u);
}

// ---------------- single-block exclusive scan: off/cursor ----------------
__global__ __launch_bounds__(1024) void k_scan(
    const unsigned* __restrict__ cnt, int n,
    int* __restrict__ off, int* __restrict__ cursor)
{
    __shared__ int wsum[17];
    __shared__ int carry_s;
    if (threadIdx.x == 0) carry_s = 0;
    __syncthreads();
    const int lane = threadIdx.x & 63, wid = threadIdx.x >> 6;
    for (int base = 0; base < n; base += 1024) {
        int i = base + (int)threadIdx.x;
        int v = (i < n) ? (int)cnt[i] : 0;
        int x = v;
        #pragma unroll
        for (int s = 1; s < 64; s <<= 1) {
            int t = __shfl_up(x, s, 64);
            if (lane >= s) x += t;
        }
        if (lane == 63) wsum[wid] = x;
        __syncthreads();
        if (threadIdx.x == 0) {
            int run = 0;
            #pragma unroll
            for (int w = 0; w < 16; ++w) { int t = wsum[w]; wsum[w] = run; run += t; }
            wsum[16] = run;
        }
        __syncthreads();
        int excl = x - v + wsum[wid] + carry_s;
        if (i < n) { off[i] = excl; cursor[i] = excl; }
        __syncthreads();
        if (threadIdx.x == 0) carry_s += wsum[16];
        __syncthreads();
    }
    if (threadIdx.x == 0) off[n] = carry_s;
}

// ---------------- bucket fill ----------------
__global__ void k_fill(const int* __restrict__ src, const int* __restrict__ dst,
                       int n, int dbase, int* __restrict__ cursor,
                       int* __restrict__ bucket)
{
    for (int i = blockIdx.x * blockDim.x + threadIdx.x; i < n;
         i += gridDim.x * blockDim.x) {
        int pos = atomicAdd(&cursor[dbase + dst[i]], 1);
        bucket[pos] = src[i];
    }
}

// ---------------- CSR gather -> mean ----------------
__global__ __launch_bounds__(256) void k_gather(
    const int* __restrict__ off, const int* __restrict__ bucket,
    const float* __restrict__ x, float* __restrict__ out, int obase, int M)
{
    const int lane = threadIdx.x & 63;
    const int w = (int)((blockIdx.x * blockDim.x + threadIdx.x) >> 6);
    if (w >= M) return;
    int o0 = off[obase + w], o1 = off[obase + w + 1];
    float a0 = 0.f, a1 = 0.f, a2 = 0.f, a3 = 0.f;
    int e = o0;
    for (; e + 4 <= o1; e += 4) {
        int s0 = bucket[e], s1 = bucket[e + 1], s2 = bucket[e + 2], s3 = bucket[e + 3];
        a0 += x[(size_t)s0 * HF + lane];
        a1 += x[(size_t)s1 * HF + lane];
        a2 += x[(size_t)s2 * HF + lane];
        a3 += x[(size_t)s3 * HF + lane];
    }
    for (; e < o1; ++e) a0 += x[(size_t)bucket[e] * HF + lane];
    float acc = (a0 + a1) + (a2 + a3);
    float inv = 1.f / fmaxf((float)(o1 - o0), 1.f);
    out[(size_t)w * HF + lane] = acc * inv;
}

// ---------------- news layer-1: xn = LN(relu(mean@Wl + bl + xn0@Wr)) ----------------
__global__ __launch_bounds__(256) void k_news_l1(
    const float* __restrict__ mean_sim, const float* __restrict__ xn0,
    const float* __restrict__ Wl, const float* __restrict__ bl,
    const float* __restrict__ Wr,
    const float* __restrict__ g, const float* __restrict__ be,
    float* __restrict__ xn, int M)
{
    __shared__ float A1[64][68];
    __shared__ float A2[64][68];
    const int t = threadIdx.x;
    const int r0 = blockIdx.x * 64;
    const int lrow = t & 63;
    const int wq = t >> 6;

    bool rok = (r0 + lrow) < M;
    #pragma unroll
    for (int j4 = 0; j4 < 4; ++j4) {
        int k0 = wq * 16 + j4 * 4;
        float4 v1 = make_float4(0.f, 0.f, 0.f, 0.f), v2 = v1;
        if (rok) {
            v1 = *(const float4*)&mean_sim[(size_t)(r0 + lrow) * HF + k0];
            v2 = *(const float4*)&xn0[(size_t)(r0 + lrow) * HF + k0];
        }
        A1[k0 + 0][lrow] = v1.x; A1[k0 + 1][lrow] = v1.y;
        A1[k0 + 2][lrow] = v1.z; A1[k0 + 3][lrow] = v1.w;
        A2[k0 + 0][lrow] = v2.x; A2[k0 + 1][lrow] = v2.y;
        A2[k0 + 2][lrow] = v2.z; A2[k0 + 3][lrow] = v2.w;
    }
    __syncthreads();

    const int rt = t >> 4, ct = t & 15;
    float acc[4][4] = {};
    #pragma unroll 16
    for (int kk = 0; kk < 64; ++kk) {
        float4 a1 = *(const float4*)&A1[kk][rt * 4];
        float4 a2 = *(const float4*)&A2[kk][rt * 4];
        float4 wl = *(const float4*)&Wl[(size_t)kk * HF + ct * 4];
        float4 wr = *(const float4*)&Wr[(size_t)kk * HF + ct * 4];
        float a1v[4] = {a1.x, a1.y, a1.z, a1.w};
        float a2v[4] = {a2.x, a2.y, a2.z, a2.w};
        float wlv[4] = {wl.x, wl.y, wl.z, wl.w};
        float wrv[4] = {wr.x, wr.y, wr.z, wr.w};
        #pragma unroll
        for (int i = 0; i < 4; ++i)
            #pragma unroll
            for (int j = 0; j < 4; ++j)
                acc[i][j] += a1v[i] * wlv[j] + a2v[i] * wrv[j];
    }
    __syncthreads();
    float (*C)[68] = A1;
    float4 blv = *(const float4*)&bl[ct * 4];
    float blb[4] = {blv.x, blv.y, blv.z, blv.w};
    #pragma unroll
    for (int i = 0; i < 4; ++i) {
        float4 o;
        o.x = fmaxf(acc[i][0] + blb[0], 0.f);
        o.y = fmaxf(acc[i][1] + blb[1], 0.f);
        o.z = fmaxf(acc[i][2] + blb[2], 0.f);
        o.w = fmaxf(acc[i][3] + blb[3], 0.f);
        *(float4*)&C[rt * 4 + i][ct * 4] = o;
    }
    __syncthreads();

    const int lane = t & 63, wid = t >> 6;
    float gl = g[lane], bel = be[lane];
    for (int rr = 0; rr < 16; ++rr) {
        int row = wid * 16 + rr;
        float v = C[row][lane];
        float s = v, q = v * v;
        #pragma unroll
        for (int m = 1; m < 64; m <<= 1) {
            s += __shfl_xor(s, m, 64);
            q += __shfl_xor(q, m, 64);
        }
        float mean = s * (1.f / 64.f);
        float var = q * (1.f / 64.f) - mean * mean;
        float r = rsqrtf(var + 1e-5f);
        int grow = r0 + row;
        if (grow < M) xn[(size_t)grow * HF + lane] = (v - mean) * r * gl + bel;
    }
}

// ---------------- company layer-1 ----------------
__global__ __launch_bounds__(256) void k_comp_l1(
    const float* __restrict__ mean_men, const float* __restrict__ mean_rel,
    const float* __restrict__ xc0,
    const float* __restrict__ Wl1, const float* __restrict__ bl1,
    const float* __restrict__ Wr1,
    const float* __restrict__ Wl2, const float* __restrict__ bl2,
    const float* __restrict__ Wr2,
    const float* __restrict__ g, const float* __restrict__ be,
    float* __restrict__ xc, int M)
{
    const int lane = threadIdx.x & 63;
    const int node = (int)((blockIdx.x * blockDim.x + threadIdx.x) >> 6);
    if (node >= M) return;
    float mm = mean_men[(size_t)node * HF + lane];
    float mr = mean_rel[(size_t)node * HF + lane];
    float xv = xc0[(size_t)node * HF + lane];
    float acc = bl1[lane] + bl2[lane];
    #pragma unroll 8
    for (int k = 0; k < 64; ++k) {
        float amm = __shfl(mm, k, 64);
        float amr = __shfl(mr, k, 64);
        float ax  = __shfl(xv, k, 64);
        acc += amm * Wl1[k * HF + lane] + ax * Wr1[k * HF + lane]
             + amr * Wl2[k * HF + lane] + ax * Wr2[k * HF + lane];
    }
    float pre = fmaxf(acc + xv, 0.f);
    float s = pre, q = pre * pre;
    #pragma unroll
    for (int m = 1; m < 64; m <<= 1) {
        s += __shfl_xor(s, m, 64);
        q += __shfl_xor(q, m, 64);
    }
    float mean = s * (1.f / 64.f);
    float var = q * (1.f / 64.f) - mean * mean;
    float r = rsqrtf(var + 1e-5f);
    xc[(size_t)node * HF + lane] = (pre - mean) * r * g[lane] + be[lane];
}

// ---------------- company layer-2 + classifier ----------------
__global__ __launch_bounds__(256) void k_final(
    const float* __restrict__ mean_men, const float* __restrict__ mean_rel,
    const float* __restrict__ xc,
    const float* __restrict__ Wl1, const float* __restrict__ bl1,
    const float* __restrict__ Wr1,
    const float* __restrict__ Wl2, const float* __restrict__ bl2,
    const float* __restrict__ Wr2,
    const float* __restrict__ W1, const float* __restrict__ b1,
    const float* __restrict__ W2, const float* __restrict__ b2,
    float* __restrict__ out, int M)
{
    const int lane = threadIdx.x & 63;
    const int node = (int)((blockIdx.x * blockDim.x + threadIdx.x) >> 6);
    if (node >= M) return;
    float mm = mean_men[(size_t)node * HF + lane];
    float mr = mean_rel[(size_t)node * HF + lane];
    float xv = xc[(size_t)node * HF + lane];
    float acc = bl1[lane] + bl2[lane];
    #pragma unroll 8
    for (int k = 0; k < 64; ++k) {
        float amm = __shfl(mm, k, 64);
        float amr = __shfl(mr, k, 64);
        float ax  = __shfl(xv, k, 64);
        acc += amm * Wl1[k * HF + lane] + ax * (Wr1[k * HF + lane] + Wr2[k * HF + lane])
             + amr * Wl2[k * HF + lane];
    }
    float comp = fmaxf(acc + xv, 0.f);
    const int l31 = lane & 31;
    float hacc = b1[l31];
    #pragma unroll 8
    for (int j = 0; j < 64; ++j) {
        float cj = __shfl(comp, j, 64);
        hacc += cj * W1[j * 32 + l31];
    }
    float h = fmaxf(hacc, 0.f);
    float p = (lane < 32) ? h * W2[l31] : 0.f;
    #pragma unroll
    for (int m = 16; m >= 1; m >>= 1) p += __shfl_xor(p, m, 64);
    if (lane == 0) out[node] = p + b2[0];
}

extern "C" void kernel_launch(void* const* d_in, const int* in_sizes, int n_in,
                              void* d_out, int out_size, void* d_ws, size_t ws_size,
                              hipStream_t stream)
{
    const float* x_news  = (const float*)d_in[0];
    const float* x_comp  = (const float*)d_in[1];
    const int*   edge_sim = (const int*)d_in[2];
    const int*   men_src  = (const int*)d_in[3];
    const int*   men_dst  = (const int*)d_in[4];
    const int*   edge_rel = (const int*)d_in[5];
    const float* nw_W = (const float*)d_in[6];
    const float* nw_b = (const float*)d_in[7];
    const float* cw_W = (const float*)d_in[8];
    const float* cw_b = (const float*)d_in[9];
    const float* n1n_g = (const float*)d_in[10];
    const float* n1n_b = (const float*)d_in[11];
    const float* n1c_g = (const float*)d_in[12];
    const float* n1c_b = (const float*)d_in[13];
    const float* c1_Wl = (const float*)d_in[14];
    const float* c1_bl = (const float*)d_in[15];
    const float* c1_Wr = (const float*)d_in[16];
    const float* c2_Wl = (const float*)d_in[17];
    const float* c2_bl = (const float*)d_in[18];
    const float* c2_Wr = (const float*)d_in[19];
    const float* cls_W1 = (const float*)d_in[20];
    const float* cls_b1 = (const float*)d_in[21];
    const float* cls_W2 = (const float*)d_in[22];
    const float* cls_b2 = (const float*)d_in[23];

    const int Nn = in_sizes[0] / 385;
    const int Nc = in_sizes[1] / 24;
    const int Es = in_sizes[2] / 2;
    const int Em = in_sizes[3];
    const int Er = in_sizes[5] / 2;
    const int* sim_src = edge_sim;
    const int* sim_dst = edge_sim + Es;
    const int* rel_src = edge_rel;
    const int* rel_dst = edge_rel + Er;
    const int ND = Nn + 2 * Nc;           // unified dst space
    const int E  = Es + Em + Er;

    float* ws = (float*)d_ws;
    size_t o = 0;
    unsigned* cnt = (unsigned*)(ws + o); o += ND;          // zeroed below
    int* off    = (int*)(ws + o); o += ND + 1;
    int* cursor = (int*)(ws + o); o += ND;
    int* bucket = (int*)(ws + o); o += E;
    float* mean_sim = ws + o; o += (size_t)Nn * HF;        // reused for l2 means
    float* mean_men1 = ws + o; o += (size_t)Nc * HF;
    float* mean_rel1 = ws + o; o += (size_t)Nc * HF;
    float* xn0 = ws + o; o += (size_t)Nn * HF;
    float* xn  = ws + o; o += (size_t)Nn * HF;
    float* xc0 = ws + o; o += (size_t)Nc * HF;
    float* xc  = ws + o; o += (size_t)Nc * HF;
    float* mean_men2 = mean_sim;                           // alias (dead after k_news_l1)
    float* mean_rel2 = mean_sim + (size_t)Nc * HF;

    hipMemsetAsync(cnt, 0, (size_t)ND * sizeof(unsigned), stream);

    // projections
    k_proj_news<<<(Nn + 63) / 64, 256, 0, stream>>>(x_news, nw_W, nw_b, xn0, Nn);
    k_proj_comp<<<(Nc * HF + 255) / 256, 256, 0, stream>>>(x_comp, cw_W, cw_b, xc0, Nc);

    // CSR build (unified over all three relations)
    k_count<<<1024, 256, 0, stream>>>(sim_dst, Es, 0, cnt);
    k_count<<<512, 256, 0, stream>>>(men_dst, Em, Nn, cnt);
    k_count<<<256, 256, 0, stream>>>(rel_dst, Er, Nn + Nc, cnt);
    k_scan<<<1, 1024, 0, stream>>>(cnt, ND, off, cursor);
    k_fill<<<1024, 256, 0, stream>>>(sim_src, sim_dst, Es, 0, cursor, bucket);
    k_fill<<<512, 256, 0, stream>>>(men_src, men_dst, Em, Nn, cursor, bucket);
    k_fill<<<256, 256, 0, stream>>>(rel_src, rel_dst, Er, Nn + Nc, cursor, bucket);

    // layer-1 aggregations (gather, one write per dst)
    k_gather<<<(Nn + 3) / 4, 256, 0, stream>>>(off, bucket, xn0, mean_sim, 0, Nn);
    k_gather<<<(Nc + 3) / 4, 256, 0, stream>>>(off, bucket, xn0, mean_men1, Nn, Nc);
    k_gather<<<(Nc + 3) / 4, 256, 0, stream>>>(off, bucket, xc0, mean_rel1, Nn + Nc, Nc);

    k_news_l1<<<(Nn + 63) / 64, 256, 0, stream>>>(
        mean_sim, xn0, c1_Wl, c1_bl, c1_Wr, n1n_g, n1n_b, xn, Nn);
    k_comp_l1<<<(Nc * HF + 255) / 256, 256, 0, stream>>>(
        mean_men1, mean_rel1, xc0,
        c1_Wl + 4096, c1_bl + 64, c1_Wr + 4096,
        c1_Wl + 8192, c1_bl + 128, c1_Wr + 8192,
        n1c_g, n1c_b, xc, Nc);

    // layer-2 aggregations (same CSR, new features)
    k_gather<<<(Nc + 3) / 4, 256, 0, stream>>>(off, bucket, xn, mean_men2, Nn, Nc);
    k_gather<<<(Nc + 3) / 4, 256, 0, stream>>>(off, bucket, xc, mean_rel2, Nn + Nc, Nc);

    k_final<<<(Nc * HF + 255) / 256, 256, 0, stream>>>(
        mean_men2, mean_rel2, xc,
        c2_Wl + 4096, c2_bl + 64, c2_Wr + 4096,
        c2_Wl + 8192, c2_bl + 128, c2_Wr + 8192,
        cls_W1, cls_b1, cls_W2, cls_b2, (float*)d_out, Nc);
}